// Round 16
// baseline (289.766 us; speedup 1.0000x reference)
//
#include <hip/hip_runtime.h>
#include <hip/hip_fp16.h>

#define NN 50000
#define NE 800000
#define DEPTH 4
#define EPSF 1e-5f
#define GTAB 8192          // nearest-neighbor table: 8193 rows of 64 f16
#define GROWS (GTAB + 1)
#define NWAVE 8192         // 2048 blocks x 4 waves (persistent, 8 blocks/CU)
#define NBKT 196           // ceil(NN/256) dst buckets
#define BK_BLOCKS 256
#define EPB (NE / BK_BLOCKS)   // 3125 edges per bucket-pass block (exact)
#define CSR_MAXE 8192      // LDS staging cap per bucket

typedef _Float16 f16;
typedef _Float16 f16x8 __attribute__((ext_vector_type(8)));
typedef float f32x4 __attribute__((ext_vector_type(4)));

#define MFMA16(a, b, c) __builtin_amdgcn_mfma_f32_16x16x32_f16(a, b, c, 0, 0, 0)

static __device__ __forceinline__ float silu_f(float x) {
    float e = __builtin_amdgcn_exp2f(x * -1.44269504088896f);
    return x * __builtin_amdgcn_rcpf(1.0f + e);
}

// ---------- merged prep: weight transpose + h0 + G tables + bucket hist ----------
#define WT_TOTAL (2 * DEPTH * (8192 + 4096))
#define NB_P0 ((WT_TOTAL + NN * 64 + 255) / 256)
#define NB_GT ((DEPTH * GROWS + 3) / 4)
#define NB_BH BK_BLOCKS
#define NB_PREP (NB_P0 + NB_GT + NB_BH)

__global__ void k_prep(const float* __restrict__ mW1, const float* __restrict__ mW2,
                       const float* __restrict__ uW1, const float* __restrict__ uW2,
                       f16* __restrict__ w1t, f16* __restrict__ w2t,
                       f16* __restrict__ u1t, f16* __restrict__ u2t,
                       const float* __restrict__ x, const float* __restrict__ nW,
                       const float* __restrict__ nb, f16* __restrict__ h16,
                       const float* __restrict__ eW, const float* __restrict__ eb,
                       const float* __restrict__ mb1, f16* __restrict__ G,
                       const int* __restrict__ ei, int* __restrict__ ghist) {
    __shared__ int hist[NBKT];
    __shared__ float es[4][64];
    int blk = blockIdx.x;
    int tid = threadIdx.x;

    if (blk < NB_P0) {
        // -- weight transpose [D][K][64] f32 -> [D][64][K] f16, then h0 init --
        int i = blk * 256 + tid;
        const int A = DEPTH * 8192, B = DEPTH * 4096;
        if (i < WT_TOTAL) {
            const float* src; f16* dst; int K, rel;
            if (i < A)              { src = mW1; dst = w1t; K = 128; rel = i; }
            else if (i < A + B)     { src = mW2; dst = w2t; K = 64;  rel = i - A; }
            else if (i < 2 * A + B) { src = uW1; dst = u1t; K = 128; rel = i - A - B; }
            else                    { src = uW2; dst = u2t; K = 64;  rel = i - 2 * A - B; }
            int kc = K * 64;
            int d = rel / kc, r = rel - d * kc;
            int k = r / 64, c = r - k * 64;
            dst[d * kc + c * K + k] = (f16)src[rel];
        } else {
            int j = i - WT_TOTAL;
            if (j < NN * 64) {
                int n = j >> 6, u = j & 63;
                h16[j] = (f16)silu_f(fmaf(x[2 * n], nW[u],
                                          fmaf(x[2 * n + 1], nW[64 + u], nb[u])));
            }
        }
    } else if (blk < NB_P0 + NB_GT) {
        // -- G tables: G[l][i][c] = b1[c] + sum_u silu(x_i*eW[u]+eb[u])*W1[64+u][c] --
        int w = tid >> 6, lane = tid & 63;
        int rowid = (blk - NB_P0) * 4 + w;
        if (rowid < DEPTH * GROWS) {
            int l = rowid / GROWS, i = rowid - l * GROWS;
            float xv = (float)i * (1.0f / GTAB);
            es[w][lane] = silu_f(fmaf(xv, eW[lane], eb[lane]));
            float s = mb1[l * 64 + lane];
            const float* Wl = mW1 + (size_t)l * 8192;
            #pragma unroll 8
            for (int u = 0; u < 64; ++u)
                s = fmaf(es[w][u], Wl[(64 + u) * 64 + lane], s);
            G[(size_t)rowid * 64 + lane] = (f16)s;
        }
    } else {
        // -- bucket histogram (LDS atomics only) --
        int b = blk - NB_P0 - NB_GT;
        for (int i = tid; i < NBKT; i += 256) hist[i] = 0;
        __syncthreads();
        int base = b * EPB;
        for (int it = 0; it < EPB; it += 256) {
            if (it + tid < EPB) atomicAdd(&hist[ei[NE + base + it + tid] >> 8], 1);
        }
        __syncthreads();
        for (int bb = tid; bb < NBKT; bb += 256)
            ghist[bb * BK_BLOCKS + b] = hist[bb];
    }
}

// ---------- CSR scan: both levels in one block (16 waves) ----------
__global__ __launch_bounds__(1024)
void k_bscan(int* __restrict__ ghist, int* __restrict__ bstart) {
    __shared__ int tot[NBKT];
    int tid = threadIdx.x, lane = tid & 63, w = tid >> 6;
    for (int b = w; b < NBKT; b += 16) {
        int carry = 0;
        #pragma unroll
        for (int c = 0; c < 4; ++c) {
            int idx = b * BK_BLOCKS + c * 64 + lane;
            int v = ghist[idx];
            int incl = v;
            #pragma unroll
            for (int off = 1; off < 64; off <<= 1) {
                int t = __shfl_up(incl, off, 64);
                if (lane >= off) incl += t;
            }
            ghist[idx] = incl - v + carry;
            carry += __shfl(incl, 63, 64);
        }
        if (lane == 0) tot[b] = carry;
    }
    __syncthreads();
    if (tid < 64) {   // wave 0: scan 196 bucket totals -> bstart
        int carry = 0;
        #pragma unroll
        for (int c = 0; c < 4; ++c) {
            int i = c * 64 + tid;
            int v = (i < NBKT) ? tot[i] : 0;
            int incl = v;
            #pragma unroll
            for (int off = 1; off < 64; off <<= 1) {
                int t = __shfl_up(incl, off, 64);
                if (tid >= off) incl += t;
            }
            if (i < NBKT) bstart[i] = incl - v + carry;
            carry += __shfl(incl, 63, 64);
        }
        if (tid == 0) bstart[NBKT] = carry;   // == NE
    }
}

// ---------- CSR pass 1c: bucket-grouped scatter via LDS staging ----------
__global__ __launch_bounds__(256)
void k_bscatter(const int* __restrict__ ei, const float* __restrict__ ea,
                const int* __restrict__ goff, const int* __restrict__ bstart,
                unsigned long long* __restrict__ btmp) {
    __shared__ int hist[NBKT], lbase[NBKT], cur[NBKT], gbase[NBKT];
    __shared__ unsigned long long stg[EPB];   // 25 KB
    int tid = threadIdx.x;
    for (int i = tid; i < NBKT; i += 256) hist[i] = 0;
    __syncthreads();
    int base = blockIdx.x * EPB;
    for (int it = 0; it < EPB; it += 256) {
        if (it + tid < EPB) atomicAdd(&hist[ei[NE + base + it + tid] >> 8], 1);
    }
    __syncthreads();
    if (tid == 0) {
        int run = 0;
        for (int b = 0; b < NBKT; ++b) { lbase[b] = run; cur[b] = run; run += hist[b]; }
    }
    __syncthreads();
    if (tid < NBKT) gbase[tid] = goff[tid * BK_BLOCKS + blockIdx.x] + bstart[tid];
    __syncthreads();
    for (int it = 0; it < EPB; it += 256) {
        if (it + tid < EPB) {
            int j = base + it + tid;
            int d = ei[NE + j];
            int src = ei[j];
            int gi = (int)fmaf(ea[j], (float)GTAB, 0.5f);
            gi = gi > GTAB ? GTAB : gi;
            unsigned long long e = ((unsigned long long)(unsigned int)d << 32)
                                 | ((unsigned long long)(((unsigned int)gi << 16) | (unsigned int)src));
            int p = atomicAdd(&cur[d >> 8], 1);
            stg[p] = e;
        }
    }
    __syncthreads();
    for (int i = tid; i < EPB; i += 256) {
        unsigned long long e = stg[i];
        int b = (int)(e >> 40);
        btmp[gbase[b] + (i - lbase[b])] = e;
    }
}

// ---------- CSR pass 2: per-bucket rowptr + epack finalize ----------
__global__ __launch_bounds__(1024)
void k_csr(const unsigned long long* __restrict__ btmp, const int* __restrict__ bstart,
           int* __restrict__ rowptr, unsigned int* __restrict__ epack) {
    __shared__ int hist[256], sbase[256], cur[256];
    __shared__ unsigned int stg[CSR_MAXE];    // 32 KB
    int tid = threadIdx.x;
    int b = blockIdx.x;
    int e0 = bstart[b], e1 = bstart[b + 1];
    int ne = e1 - e0;
    int n0 = b << 8;
    int nn = NN - n0; if (nn > 256) nn = 256;
    if (tid < 256) hist[tid] = 0;
    __syncthreads();
    for (int i = tid; i < ne; i += 1024)
        atomicAdd(&hist[(int)(btmp[e0 + i] >> 32) - n0], 1);
    __syncthreads();
    if (tid == 0) {
        int run = e0;
        for (int i = 0; i < 256; ++i) { sbase[i] = run; cur[i] = run - e0; run += hist[i]; }
    }
    __syncthreads();
    if (tid < nn) rowptr[n0 + tid] = sbase[tid];
    if (b == NBKT - 1 && tid == 0) rowptr[NN] = NE;
    bool fits = (ne <= CSR_MAXE);
    for (int i = tid; i < ne; i += 1024) {
        unsigned long long e = btmp[e0 + i];
        int local = (int)(e >> 32) - n0;
        int p = atomicAdd(&cur[local], 1);
        if (fits) stg[p] = (unsigned int)e;
        else epack[e0 + p] = (unsigned int)e;
    }
    __syncthreads();
    if (fits)
        for (int i = tid; i < ne; i += 1024) epack[e0 + i] = stg[i];
}

// ---------- H' = h @ W1a  (layer 0 only; later layers fused into k_node) ----------
#define HP_TILES 3125
#define HP_BLOCKS 391

__global__ __launch_bounds__(512, 4)
void k_hprime(const f16* __restrict__ h16, const f16* __restrict__ w1t,
              f16* __restrict__ hp16) {
    __shared__ f16 wa[64 * 64];
    int tid = threadIdx.x;
    {
        int g = tid;
        int c = g >> 3, k0 = (g & 7) << 3;
        f16x8 v = *(const f16x8*)&w1t[c * 128 + k0];
        *(f16x8*)&wa[(c << 6) | (k0 ^ ((c & 7) << 3))] = v;
    }
    __syncthreads();

    int w = tid >> 6, lane = tid & 63;
    int row = lane & 15, g4 = lane >> 4;

    int tile = blockIdx.x * 8 + w;
    if (tile >= HP_TILES) return;
    int n0 = tile * 16;
    int nA = n0 + row;

    f16x8 ha0 = *(const f16x8*)&h16[(size_t)nA * 64 + g4 * 8];
    f16x8 ha1 = *(const f16x8*)&h16[(size_t)nA * 64 + 32 + g4 * 8];

    int nC = n0 + g4 * 4;
    #pragma unroll
    for (int cb = 0; cb < 4; ++cb) {
        int c = row + 16 * cb;
        f32x4 acc = (f32x4){0.f, 0.f, 0.f, 0.f};
        f16x8 wb0 = *(const f16x8*)&wa[(c << 6) | ((g4 * 8) ^ ((c & 7) << 3))];
        f16x8 wb1 = *(const f16x8*)&wa[(c << 6) | ((32 + g4 * 8) ^ ((c & 7) << 3))];
        acc = MFMA16(ha0, wb0, acc);
        acc = MFMA16(ha1, wb1, acc);
        #pragma unroll
        for (int v = 0; v < 4; ++v)
            hp16[(size_t)(nC + v) * 64 + c] = (f16)acc[v];
    }
}

// ---------- edge kernel: pure-VALU, persistent, self-partitioning; f16 MEAN out ----------
#define EK_BLOCKS (NWAVE / 4)   // 2048

__global__ __launch_bounds__(256, 8)
void k_edge(const int* __restrict__ rowptr, const unsigned int* __restrict__ epack,
            const f16* __restrict__ hp16, const f16* __restrict__ G0,
            f16* __restrict__ Sm) {
    int tid = threadIdx.x;
    int w = tid >> 6, lane = tid & 63;
    int gw = blockIdx.x * 4 + w;

    // parallel binary search: even lanes find start(gw), odd lanes start(gw+1)
    int target = (int)(((long long)(gw + (lane & 1)) * NE) / NWAVE);
    int lo = 0, hi = NN;
    while (lo < hi) {
        int mid = (lo + hi) >> 1;
        if (rowptr[mid] >= target) hi = mid; else lo = mid + 1;
    }
    int nbeg = __shfl(lo, 0, 64);
    int nend = __shfl(lo, 1, 64);

    for (int n = nbeg; n < nend; ++n) {
        int kb0 = rowptr[n], ke = rowptr[n + 1];
        if (ke <= kb0) continue;   // deg-0: row left unwritten; k_node masks it
        float acc = 0.f;
        int p = kb0;

        for (; p + 8 <= ke; p += 8) {
            unsigned int k0 = epack[p],     k1 = epack[p + 1],
                         k2 = epack[p + 2], k3 = epack[p + 3],
                         k4 = epack[p + 4], k5 = epack[p + 5],
                         k6 = epack[p + 6], k7 = epack[p + 7];
            float hv0 = (float)hp16[(size_t)(k0 & 0xFFFFu) * 64 + lane];
            float hv1 = (float)hp16[(size_t)(k1 & 0xFFFFu) * 64 + lane];
            float hv2 = (float)hp16[(size_t)(k2 & 0xFFFFu) * 64 + lane];
            float hv3 = (float)hp16[(size_t)(k3 & 0xFFFFu) * 64 + lane];
            float hv4 = (float)hp16[(size_t)(k4 & 0xFFFFu) * 64 + lane];
            float hv5 = (float)hp16[(size_t)(k5 & 0xFFFFu) * 64 + lane];
            float hv6 = (float)hp16[(size_t)(k6 & 0xFFFFu) * 64 + lane];
            float hv7 = (float)hp16[(size_t)(k7 & 0xFFFFu) * 64 + lane];
            float g0 = (float)G0[(size_t)(k0 >> 16) * 64 + lane];
            float g1 = (float)G0[(size_t)(k1 >> 16) * 64 + lane];
            float g2 = (float)G0[(size_t)(k2 >> 16) * 64 + lane];
            float g3 = (float)G0[(size_t)(k3 >> 16) * 64 + lane];
            float g4v = (float)G0[(size_t)(k4 >> 16) * 64 + lane];
            float g5 = (float)G0[(size_t)(k5 >> 16) * 64 + lane];
            float g6 = (float)G0[(size_t)(k6 >> 16) * 64 + lane];
            float g7 = (float)G0[(size_t)(k7 >> 16) * 64 + lane];
            acc += silu_f(hv0 + g0) + silu_f(hv1 + g1)
                 + silu_f(hv2 + g2) + silu_f(hv3 + g3)
                 + silu_f(hv4 + g4v) + silu_f(hv5 + g5)
                 + silu_f(hv6 + g6) + silu_f(hv7 + g7);
        }
        for (; p + 4 <= ke; p += 4) {
            unsigned int k0 = epack[p],     k1 = epack[p + 1],
                         k2 = epack[p + 2], k3 = epack[p + 3];
            float hv0 = (float)hp16[(size_t)(k0 & 0xFFFFu) * 64 + lane];
            float hv1 = (float)hp16[(size_t)(k1 & 0xFFFFu) * 64 + lane];
            float hv2 = (float)hp16[(size_t)(k2 & 0xFFFFu) * 64 + lane];
            float hv3 = (float)hp16[(size_t)(k3 & 0xFFFFu) * 64 + lane];
            float g0 = (float)G0[(size_t)(k0 >> 16) * 64 + lane];
            float g1 = (float)G0[(size_t)(k1 >> 16) * 64 + lane];
            float g2 = (float)G0[(size_t)(k2 >> 16) * 64 + lane];
            float g3 = (float)G0[(size_t)(k3 >> 16) * 64 + lane];
            acc += silu_f(hv0 + g0) + silu_f(hv1 + g1)
                 + silu_f(hv2 + g2) + silu_f(hv3 + g3);
        }
        for (; p < ke; ++p) {
            unsigned int k0 = epack[p];
            acc += silu_f((float)hp16[(size_t)(k0 & 0xFFFFu) * 64 + lane]
                        + (float)G0[(size_t)(k0 >> 16) * 64 + lane]);
        }
        float m = acc * __builtin_amdgcn_rcpf((float)(ke - kb0));
        Sm[(size_t)n * 64 + lane] = (f16)m;
    }
}

// ---------- node kernel: aggr MLP + f16 residual + LN + fused next H' ----------
#define NK_TILES 3125
#define NK_BLOCKS 391

__global__ __launch_bounds__(512, 6)
void k_node(const f16* __restrict__ h16, const f16* __restrict__ Sm,
            const int* __restrict__ rowptr,
            const f16* __restrict__ w2t, const float* __restrict__ b2,
            const f16* __restrict__ u1t, const float* __restrict__ b1u,
            const f16* __restrict__ u2t, const float* __restrict__ b2u,
            const float* __restrict__ lng, const float* __restrict__ lnb,
            const f16* __restrict__ w1an,
            f16* __restrict__ h16o, f16* __restrict__ hp16o,
            float* __restrict__ out32) {
    __shared__ f16 u1s[64 * 128];
    __shared__ f16 w2s[64 * 64], u2s[64 * 64];
    __shared__ float b2s[64], b1us[64], b2us[64], lngs[64], lnbs[64];
    __shared__ f16 trs[8][16 * 64];

    int tid = threadIdx.x;
    {
        const f16x8* u1v = (const f16x8*)u1t;
        #pragma unroll
        for (int it = 0; it < 2; ++it) {
            int g = tid + it * 512;
            int c = g >> 4, k0 = (g & 15) << 3;
            *(f16x8*)&u1s[(c << 7) | (k0 ^ ((c & 7) << 3))] = u1v[g];
        }
        const f16x8* w2v = (const f16x8*)w2t;
        const f16x8* u2v = (const f16x8*)u2t;
        {
            int g = tid;
            int c = g >> 3, k0 = (g & 7) << 3;
            int pp = (c << 6) | (k0 ^ ((c & 7) << 3));
            *(f16x8*)&w2s[pp] = w2v[g];
            *(f16x8*)&u2s[pp] = u2v[g];
        }
    }
    if (tid < 64) {
        b2s[tid] = b2[tid]; b1us[tid] = b1u[tid]; b2us[tid] = b2u[tid];
        lngs[tid] = lng[tid]; lnbs[tid] = lnb[tid];
    }
    __syncthreads();

    int w = tid >> 6, lane = tid & 63;
    int row = lane & 15, g4 = lane >> 4;
    f16* tp = trs[w];

    int tile = blockIdx.x * 8 + w;
    if (tile >= NK_TILES) return;
    int n0 = tile * 16;
    int nA = n0 + row;

    // ---- aggr = mean @ W2 + b2*(deg>0); Sm holds the f16 mean ----
    int degA = rowptr[nA + 1] - rowptr[nA];
    f16x8 sa0 = *(const f16x8*)&Sm[(size_t)nA * 64 + g4 * 8];
    f16x8 sa1 = *(const f16x8*)&Sm[(size_t)nA * 64 + 32 + g4 * 8];
    if (degA <= 0) {   // deg-0 rows never written: mask stale content
        #pragma unroll
        for (int j = 0; j < 8; ++j) { sa0[j] = (f16)0.f; sa1[j] = (f16)0.f; }
    }
    int nC = n0 + g4 * 4;
    int r0 = rowptr[nC], r1 = rowptr[nC + 1], r2 = rowptr[nC + 2],
        r3 = rowptr[nC + 3], r4 = rowptr[nC + 4];
    float f0 = r1 > r0 ? 1.f : 0.f;
    float f1 = r2 > r1 ? 1.f : 0.f;
    float f2 = r3 > r2 ? 1.f : 0.f;
    float f3 = r4 > r3 ? 1.f : 0.f;

    f32x4 agg[4];
    #pragma unroll
    for (int cb = 0; cb < 4; ++cb) {
        int c = row + 16 * cb;
        float bv = b2s[c];
        agg[cb] = (f32x4){bv * f0, bv * f1, bv * f2, bv * f3};
        f16x8 wb0 = *(const f16x8*)&w2s[(c << 6) | ((g4 * 8) ^ ((c & 7) << 3))];
        f16x8 wb1 = *(const f16x8*)&w2s[(c << 6) | ((32 + g4 * 8) ^ ((c & 7) << 3))];
        agg[cb] = MFMA16(sa0, wb0, agg[cb]);
        agg[cb] = MFMA16(sa1, wb1, agg[cb]);
    }

    // ---- transpose aggr (C-frag) -> A-frag via wave-private LDS ----
    #pragma unroll
    for (int cb = 0; cb < 4; ++cb) {
        int c = row + 16 * cb;
        #pragma unroll
        for (int v = 0; v < 4; ++v) {
            int r = g4 * 4 + v;
            tp[(r << 6) | (c ^ ((r & 7) << 3))] = (f16)agg[cb][v];
        }
    }
    f16x8 ha0 = *(const f16x8*)&h16[(size_t)nA * 64 + g4 * 8];
    f16x8 ha1 = *(const f16x8*)&h16[(size_t)nA * 64 + 32 + g4 * 8];
    f16x8 aa2 = *(const f16x8*)&tp[(row << 6) | ((g4 * 8) ^ ((row & 7) << 3))];
    f16x8 aa3 = *(const f16x8*)&tp[(row << 6) | ((32 + g4 * 8) ^ ((row & 7) << 3))];

    // ---- hid = silu(cat[h, aggr] @ U1 + b1u) ----
    f32x4 hid[4];
    #pragma unroll
    for (int cb = 0; cb < 4; ++cb) {
        int c = row + 16 * cb;
        float bv = b1us[c];
        hid[cb] = (f32x4){bv, bv, bv, bv};
        hid[cb] = MFMA16(ha0, *(const f16x8*)&u1s[(c << 7) | ((g4 * 8) ^ ((c & 7) << 3))], hid[cb]);
        hid[cb] = MFMA16(ha1, *(const f16x8*)&u1s[(c << 7) | ((32 + g4 * 8) ^ ((c & 7) << 3))], hid[cb]);
        hid[cb] = MFMA16(aa2, *(const f16x8*)&u1s[(c << 7) | ((64 + g4 * 8) ^ ((c & 7) << 3))], hid[cb]);
        hid[cb] = MFMA16(aa3, *(const f16x8*)&u1s[(c << 7) | ((96 + g4 * 8) ^ ((c & 7) << 3))], hid[cb]);
    }

    #pragma unroll
    for (int cb = 0; cb < 4; ++cb) {
        int c = row + 16 * cb;
        #pragma unroll
        for (int v = 0; v < 4; ++v) {
            int r = g4 * 4 + v;
            tp[(r << 6) | (c ^ ((r & 7) << 3))] = (f16)silu_f(hid[cb][v]);
        }
    }
    f16x8 za0 = *(const f16x8*)&tp[(row << 6) | ((g4 * 8) ^ ((row & 7) << 3))];
    f16x8 za1 = *(const f16x8*)&tp[(row << 6) | ((32 + g4 * 8) ^ ((row & 7) << 3))];

    f32x4 out[4];
    #pragma unroll
    for (int cb = 0; cb < 4; ++cb) {
        int c = row + 16 * cb;
        float bv = b2us[c];
        out[cb] = (f32x4){bv, bv, bv, bv};
        out[cb] = MFMA16(za0, *(const f16x8*)&u2s[(c << 6) | ((g4 * 8) ^ ((c & 7) << 3))], out[cb]);
        out[cb] = MFMA16(za1, *(const f16x8*)&u2s[(c << 6) | ((32 + g4 * 8) ^ ((c & 7) << 3))], out[cb]);
    }

    // ---- residual (f16 h) + LayerNorm; stash h_new into tp for fused next H' ----
    #pragma unroll
    for (int v = 0; v < 4; ++v) {
        int n = nC + v;
        float hp[4];
        float s = 0.f, q = 0.f;
        #pragma unroll
        for (int cb = 0; cb < 4; ++cb) {
            float xv = (float)h16[(size_t)n * 64 + row + 16 * cb] + out[cb][v];
            hp[cb] = xv; s += xv; q += xv * xv;
        }
        #pragma unroll
        for (int off = 1; off < 16; off <<= 1) {
            s += __shfl_xor(s, off, 64);
            q += __shfl_xor(q, off, 64);
        }
        float mu = s * 0.015625f;
        float var = q * 0.015625f - mu * mu;
        float rstd = __builtin_amdgcn_rsqf(var + EPSF);
        int r = g4 * 4 + v;
        #pragma unroll
        for (int cb = 0; cb < 4; ++cb) {
            int c = row + 16 * cb;
            float o = (hp[cb] - mu) * rstd * lngs[c] + lnbs[c];
            if (out32) out32[(size_t)n * 64 + c] = o;
            f16 o16 = (f16)o;
            if (h16o) h16o[(size_t)n * 64 + c] = o16;
            tp[(r << 6) | (c ^ ((r & 7) << 3))] = o16;
        }
    }

    // ---- fused next-layer H' = h_new @ W1a (B-frags from global/L2) ----
    if (w1an) {
        f16x8 pa0 = *(const f16x8*)&tp[(row << 6) | ((g4 * 8) ^ ((row & 7) << 3))];
        f16x8 pa1 = *(const f16x8*)&tp[(row << 6) | ((32 + g4 * 8) ^ ((row & 7) << 3))];
        #pragma unroll
        for (int cb = 0; cb < 4; ++cb) {
            int c = row + 16 * cb;
            f32x4 acc = (f32x4){0.f, 0.f, 0.f, 0.f};
            f16x8 wb0 = *(const f16x8*)&w1an[c * 128 + g4 * 8];
            f16x8 wb1 = *(const f16x8*)&w1an[c * 128 + 32 + g4 * 8];
            acc = MFMA16(pa0, wb0, acc);
            acc = MFMA16(pa1, wb1, acc);
            #pragma unroll
            for (int v = 0; v < 4; ++v)
                hp16o[(size_t)(nC + v) * 64 + c] = (f16)acc[v];
        }
    }
}

extern "C" void kernel_launch(void* const* d_in, const int* in_sizes, int n_in,
                              void* d_out, int out_size, void* d_ws, size_t ws_size,
                              hipStream_t stream) {
    const float* x   = (const float*)d_in[0];
    const int*   ei  = (const int*)d_in[1];
    const float* ea  = (const float*)d_in[2];
    const float* nW  = (const float*)d_in[3];
    const float* nb  = (const float*)d_in[4];
    const float* eW  = (const float*)d_in[5];
    const float* eb  = (const float*)d_in[6];
    const float* mW1 = (const float*)d_in[7];
    const float* mb1 = (const float*)d_in[8];
    const float* mW2 = (const float*)d_in[9];
    const float* mb2 = (const float*)d_in[10];
    const float* uW1 = (const float*)d_in[11];
    const float* ub1 = (const float*)d_in[12];
    const float* uW2 = (const float*)d_in[13];
    const float* ub2 = (const float*)d_in[14];
    const float* lng = (const float*)d_in[15];
    const float* lnb = (const float*)d_in[16];

    char* p = (char*)d_ws;
    f16*   Sm     = (f16*)p;    p += (size_t)NN * 64 * 2;
    f16*   h16    = (f16*)p;    p += (size_t)NN * 64 * 2;
    f16*   hp16   = (f16*)p;    p += (size_t)NN * 64 * 2;
    int*   rowptr = (int*)p;    p += (size_t)(NN + 4) * 4;
    int*   ghist  = (int*)p;    p += (size_t)NBKT * BK_BLOCKS * 4;
    int*   bstart = (int*)p;    p += (size_t)(NBKT + 4) * 4;
    unsigned int* epack = (unsigned int*)p; p += (size_t)NE * 4;
    unsigned long long* btmp = (unsigned long long*)p; p += (size_t)NE * 8;
    f16*   G      = (f16*)p;    p += (size_t)DEPTH * GROWS * 64 * 2;
    f16*   w1t = (f16*)p;    p += (size_t)DEPTH * 8192 * 2;
    f16*   w2t = (f16*)p;    p += (size_t)DEPTH * 4096 * 2;
    f16*   u1t = (f16*)p;    p += (size_t)DEPTH * 8192 * 2;
    f16*   u2t = (f16*)p;    p += (size_t)DEPTH * 4096 * 2;

    k_prep<<<NB_PREP, 256, 0, stream>>>(mW1, mW2, uW1, uW2, w1t, w2t, u1t, u2t,
                                        x, nW, nb, h16, eW, eb, mb1, G, ei, ghist);
    k_bscan<<<1, 1024, 0, stream>>>(ghist, bstart);
    k_bscatter<<<BK_BLOCKS, 256, 0, stream>>>(ei, ea, ghist, bstart, btmp);
    k_csr<<<NBKT, 1024, 0, stream>>>(btmp, bstart, rowptr, epack);
    k_hprime<<<HP_BLOCKS, 512, 0, stream>>>(h16, w1t, hp16);   // layer 0 H'

    for (int l = 0; l < DEPTH; ++l) {
        bool last = (l == DEPTH - 1);
        k_edge<<<EK_BLOCKS, 256, 0, stream>>>(rowptr, epack, hp16,
            G + (size_t)l * GROWS * 64, Sm);
        k_node<<<NK_BLOCKS, 512, 0, stream>>>(h16, Sm, rowptr,
            w2t + (size_t)l * 4096, mb2 + l * 64,
            u1t + (size_t)l * 8192, ub1 + l * 64,
            u2t + (size_t)l * 4096, ub2 + l * 64,
            lng + l * 64, lnb + l * 64,
            last ? (const f16*)nullptr : (w1t + (size_t)(l + 1) * 8192),
            last ? (f16*)nullptr : h16, hp16,
            last ? (float*)d_out : (float*)nullptr);
    }
}

// Round 17
// 263.494 us; speedup vs baseline: 1.0997x; 1.0997x over previous
//
#include <hip/hip_runtime.h>
#include <hip/hip_fp16.h>

#define NN 50000
#define NE 800000
#define DEPTH 4
#define EPSF 1e-5f
#define GTAB 8192          // nearest-neighbor table: 8193 rows of 64 f16
#define GROWS (GTAB + 1)
#define NWAVE 8192         // 2048 blocks x 4 waves (persistent, 8 blocks/CU)
#define NBKT 196           // ceil(NN/256) dst buckets
#define BK_BLOCKS 256
#define EPB (NE / BK_BLOCKS)   // 3125 edges per bucket-pass block (exact)
#define CSR_MAXE 8192      // LDS staging cap per bucket

typedef _Float16 f16;
typedef _Float16 f16x8 __attribute__((ext_vector_type(8)));
typedef float f32x4 __attribute__((ext_vector_type(4)));

#define MFMA16(a, b, c) __builtin_amdgcn_mfma_f32_16x16x32_f16(a, b, c, 0, 0, 0)

static __device__ __forceinline__ float silu_f(float x) {
    float e = __builtin_amdgcn_exp2f(x * -1.44269504088896f);
    return x * __builtin_amdgcn_rcpf(1.0f + e);
}

// ---------- merged prep: weight transpose + h0 + G tables + bucket hist ----------
#define WT_TOTAL (2 * DEPTH * (8192 + 4096))
#define NB_P0 ((WT_TOTAL + NN * 64 + 255) / 256)
#define NB_GT ((DEPTH * GROWS + 3) / 4)
#define NB_BH BK_BLOCKS
#define NB_PREP (NB_P0 + NB_GT + NB_BH)

__global__ void k_prep(const float* __restrict__ mW1, const float* __restrict__ mW2,
                       const float* __restrict__ uW1, const float* __restrict__ uW2,
                       f16* __restrict__ w1t, f16* __restrict__ w2t,
                       f16* __restrict__ u1t, f16* __restrict__ u2t,
                       const float* __restrict__ x, const float* __restrict__ nW,
                       const float* __restrict__ nb, f16* __restrict__ h16,
                       const float* __restrict__ eW, const float* __restrict__ eb,
                       const float* __restrict__ mb1, f16* __restrict__ G,
                       const int* __restrict__ ei, int* __restrict__ ghist) {
    __shared__ int hist[NBKT];
    __shared__ float es[4][64];
    int blk = blockIdx.x;
    int tid = threadIdx.x;

    if (blk < NB_P0) {
        int i = blk * 256 + tid;
        const int A = DEPTH * 8192, B = DEPTH * 4096;
        if (i < WT_TOTAL) {
            const float* src; f16* dst; int K, rel;
            if (i < A)              { src = mW1; dst = w1t; K = 128; rel = i; }
            else if (i < A + B)     { src = mW2; dst = w2t; K = 64;  rel = i - A; }
            else if (i < 2 * A + B) { src = uW1; dst = u1t; K = 128; rel = i - A - B; }
            else                    { src = uW2; dst = u2t; K = 64;  rel = i - 2 * A - B; }
            int kc = K * 64;
            int d = rel / kc, r = rel - d * kc;
            int k = r / 64, c = r - k * 64;
            dst[d * kc + c * K + k] = (f16)src[rel];
        } else {
            int j = i - WT_TOTAL;
            if (j < NN * 64) {
                int n = j >> 6, u = j & 63;
                h16[j] = (f16)silu_f(fmaf(x[2 * n], nW[u],
                                          fmaf(x[2 * n + 1], nW[64 + u], nb[u])));
            }
        }
    } else if (blk < NB_P0 + NB_GT) {
        int w = tid >> 6, lane = tid & 63;
        int rowid = (blk - NB_P0) * 4 + w;
        if (rowid < DEPTH * GROWS) {
            int l = rowid / GROWS, i = rowid - l * GROWS;
            float xv = (float)i * (1.0f / GTAB);
            es[w][lane] = silu_f(fmaf(xv, eW[lane], eb[lane]));
            float s = mb1[l * 64 + lane];
            const float* Wl = mW1 + (size_t)l * 8192;
            #pragma unroll 8
            for (int u = 0; u < 64; ++u)
                s = fmaf(es[w][u], Wl[(64 + u) * 64 + lane], s);
            G[(size_t)rowid * 64 + lane] = (f16)s;
        }
    } else {
        int b = blk - NB_P0 - NB_GT;
        for (int i = tid; i < NBKT; i += 256) hist[i] = 0;
        __syncthreads();
        int base = b * EPB;
        for (int it = 0; it < EPB; it += 256) {
            if (it + tid < EPB) atomicAdd(&hist[ei[NE + base + it + tid] >> 8], 1);
        }
        __syncthreads();
        for (int bb = tid; bb < NBKT; bb += 256)
            ghist[bb * BK_BLOCKS + b] = hist[bb];
    }
}

// ---------- CSR pass 1b-1: per-bucket parallel scan (one WAVE per bucket) ----------
__global__ __launch_bounds__(256)
void k_bscan1(int* __restrict__ ghist, int* __restrict__ tot) {
    int tid = threadIdx.x, lane = tid & 63, w = tid >> 6;
    int b = blockIdx.x * 4 + w;
    if (b >= NBKT) return;
    int carry = 0;
    #pragma unroll
    for (int c = 0; c < 4; ++c) {
        int idx = b * BK_BLOCKS + c * 64 + lane;
        int v = ghist[idx];
        int incl = v;
        #pragma unroll
        for (int off = 1; off < 64; off <<= 1) {
            int t = __shfl_up(incl, off, 64);
            if (lane >= off) incl += t;
        }
        ghist[idx] = incl - v + carry;
        carry += __shfl(incl, 63, 64);
    }
    if (lane == 0) tot[b] = carry;
}

// ---------- CSR pass 1b-2: bucket starts from totals (1 wave scan) ----------
__global__ void k_bscan2(const int* __restrict__ tot, int* __restrict__ bstart) {
    int tid = threadIdx.x;
    if (tid >= 64) return;
    int carry = 0;
    #pragma unroll
    for (int c = 0; c < 4; ++c) {
        int i = c * 64 + tid;
        int v = (i < NBKT) ? tot[i] : 0;
        int incl = v;
        #pragma unroll
        for (int off = 1; off < 64; off <<= 1) {
            int t = __shfl_up(incl, off, 64);
            if (tid >= off) incl += t;
        }
        if (i < NBKT) bstart[i] = incl - v + carry;
        carry += __shfl(incl, 63, 64);
    }
    if (tid == 0) bstart[NBKT] = carry;   // == NE
}

// ---------- CSR pass 1c: bucket-grouped scatter via LDS staging ----------
__global__ __launch_bounds__(256)
void k_bscatter(const int* __restrict__ ei, const float* __restrict__ ea,
                const int* __restrict__ goff, const int* __restrict__ bstart,
                unsigned long long* __restrict__ btmp) {
    __shared__ int hist[NBKT], lbase[NBKT], cur[NBKT], gbase[NBKT];
    __shared__ unsigned long long stg[EPB];   // 25 KB
    int tid = threadIdx.x;
    for (int i = tid; i < NBKT; i += 256) hist[i] = 0;
    __syncthreads();
    int base = blockIdx.x * EPB;
    for (int it = 0; it < EPB; it += 256) {
        if (it + tid < EPB) atomicAdd(&hist[ei[NE + base + it + tid] >> 8], 1);
    }
    __syncthreads();
    if (tid == 0) {
        int run = 0;
        for (int b = 0; b < NBKT; ++b) { lbase[b] = run; cur[b] = run; run += hist[b]; }
    }
    __syncthreads();
    if (tid < NBKT) gbase[tid] = goff[tid * BK_BLOCKS + blockIdx.x] + bstart[tid];
    __syncthreads();
    for (int it = 0; it < EPB; it += 256) {
        if (it + tid < EPB) {
            int j = base + it + tid;
            int d = ei[NE + j];
            int src = ei[j];
            int gi = (int)fmaf(ea[j], (float)GTAB, 0.5f);
            gi = gi > GTAB ? GTAB : gi;
            unsigned long long e = ((unsigned long long)(unsigned int)d << 32)
                                 | ((unsigned long long)(((unsigned int)gi << 16) | (unsigned int)src));
            int p = atomicAdd(&cur[d >> 8], 1);
            stg[p] = e;
        }
    }
    __syncthreads();
    for (int i = tid; i < EPB; i += 256) {
        unsigned long long e = stg[i];
        int b = (int)(e >> 40);
        btmp[gbase[b] + (i - lbase[b])] = e;
    }
}

// ---------- CSR pass 2: per-bucket rowptr + epack finalize ----------
__global__ __launch_bounds__(1024)
void k_csr(const unsigned long long* __restrict__ btmp, const int* __restrict__ bstart,
           int* __restrict__ rowptr, unsigned int* __restrict__ epack) {
    __shared__ int hist[256], sbase[256], cur[256];
    __shared__ unsigned int stg[CSR_MAXE];    // 32 KB
    int tid = threadIdx.x;
    int b = blockIdx.x;
    int e0 = bstart[b], e1 = bstart[b + 1];
    int ne = e1 - e0;
    int n0 = b << 8;
    int nn = NN - n0; if (nn > 256) nn = 256;
    if (tid < 256) hist[tid] = 0;
    __syncthreads();
    for (int i = tid; i < ne; i += 1024)
        atomicAdd(&hist[(int)(btmp[e0 + i] >> 32) - n0], 1);
    __syncthreads();
    if (tid == 0) {
        int run = e0;
        for (int i = 0; i < 256; ++i) { sbase[i] = run; cur[i] = run - e0; run += hist[i]; }
    }
    __syncthreads();
    if (tid < nn) rowptr[n0 + tid] = sbase[tid];
    if (b == NBKT - 1 && tid == 0) rowptr[NN] = NE;
    bool fits = (ne <= CSR_MAXE);
    for (int i = tid; i < ne; i += 1024) {
        unsigned long long e = btmp[e0 + i];
        int local = (int)(e >> 32) - n0;
        int p = atomicAdd(&cur[local], 1);
        if (fits) stg[p] = (unsigned int)e;
        else epack[e0 + p] = (unsigned int)e;
    }
    __syncthreads();
    if (fits)
        for (int i = tid; i < ne; i += 1024) epack[e0 + i] = stg[i];
}

// ---------- per-wave start nodes: edge-balanced partition over NWAVE waves ----------
__global__ void k_wstart(const int* __restrict__ rowptr, int* __restrict__ wstart) {
    int w = blockIdx.x * 256 + threadIdx.x;
    if (w > NWAVE) return;
    int target = (int)(((long long)w * NE) / NWAVE);
    int lo = 0, hi = NN;
    while (lo < hi) {
        int mid = (lo + hi) >> 1;
        if (rowptr[mid] >= target) hi = mid; else lo = mid + 1;
    }
    wstart[w] = lo;
}

// ---------- H' = h @ W1a  (layer 0 only; later layers fused into k_node) ----------
#define HP_TILES 3125
#define HP_BLOCKS 391

__global__ __launch_bounds__(512, 4)
void k_hprime(const f16* __restrict__ h16, const f16* __restrict__ w1t,
              f16* __restrict__ hp16) {
    __shared__ f16 wa[64 * 64];
    int tid = threadIdx.x;
    {
        int g = tid;
        int c = g >> 3, k0 = (g & 7) << 3;
        f16x8 v = *(const f16x8*)&w1t[c * 128 + k0];
        *(f16x8*)&wa[(c << 6) | (k0 ^ ((c & 7) << 3))] = v;
    }
    __syncthreads();

    int w = tid >> 6, lane = tid & 63;
    int row = lane & 15, g4 = lane >> 4;

    int tile = blockIdx.x * 8 + w;
    if (tile >= HP_TILES) return;
    int n0 = tile * 16;
    int nA = n0 + row;

    f16x8 ha0 = *(const f16x8*)&h16[(size_t)nA * 64 + g4 * 8];
    f16x8 ha1 = *(const f16x8*)&h16[(size_t)nA * 64 + 32 + g4 * 8];

    int nC = n0 + g4 * 4;
    #pragma unroll
    for (int cb = 0; cb < 4; ++cb) {
        int c = row + 16 * cb;
        f32x4 acc = (f32x4){0.f, 0.f, 0.f, 0.f};
        f16x8 wb0 = *(const f16x8*)&wa[(c << 6) | ((g4 * 8) ^ ((c & 7) << 3))];
        f16x8 wb1 = *(const f16x8*)&wa[(c << 6) | ((32 + g4 * 8) ^ ((c & 7) << 3))];
        acc = MFMA16(ha0, wb0, acc);
        acc = MFMA16(ha1, wb1, acc);
        #pragma unroll
        for (int v = 0; v < 4; ++v)
            hp16[(size_t)(nC + v) * 64 + c] = (f16)acc[v];
    }
}

// ---------- edge kernel: pure-VALU, persistent, edge-balanced; f16 MEAN out ----------
#define EK_BLOCKS (NWAVE / 4)   // 2048

__global__ __launch_bounds__(256, 8)
void k_edge(const int* __restrict__ rowptr, const int* __restrict__ wstart,
            const unsigned int* __restrict__ epack,
            const f16* __restrict__ hp16, const f16* __restrict__ G0,
            f16* __restrict__ Sm) {
    int tid = threadIdx.x;
    int w = tid >> 6, lane = tid & 63;

    int gw = blockIdx.x * 4 + w;
    int nbeg = wstart[gw], nend = wstart[gw + 1];

    for (int n = nbeg; n < nend; ++n) {
        int kb0 = rowptr[n], ke = rowptr[n + 1];
        if (ke <= kb0) continue;   // deg-0: row left unwritten; k_node masks it
        float acc = 0.f;
        int p = kb0;

        for (; p + 8 <= ke; p += 8) {
            unsigned int k0 = epack[p],     k1 = epack[p + 1],
                         k2 = epack[p + 2], k3 = epack[p + 3],
                         k4 = epack[p + 4], k5 = epack[p + 5],
                         k6 = epack[p + 6], k7 = epack[p + 7];
            float hv0 = (float)hp16[(size_t)(k0 & 0xFFFFu) * 64 + lane];
            float hv1 = (float)hp16[(size_t)(k1 & 0xFFFFu) * 64 + lane];
            float hv2 = (float)hp16[(size_t)(k2 & 0xFFFFu) * 64 + lane];
            float hv3 = (float)hp16[(size_t)(k3 & 0xFFFFu) * 64 + lane];
            float hv4 = (float)hp16[(size_t)(k4 & 0xFFFFu) * 64 + lane];
            float hv5 = (float)hp16[(size_t)(k5 & 0xFFFFu) * 64 + lane];
            float hv6 = (float)hp16[(size_t)(k6 & 0xFFFFu) * 64 + lane];
            float hv7 = (float)hp16[(size_t)(k7 & 0xFFFFu) * 64 + lane];
            float g0 = (float)G0[(size_t)(k0 >> 16) * 64 + lane];
            float g1 = (float)G0[(size_t)(k1 >> 16) * 64 + lane];
            float g2 = (float)G0[(size_t)(k2 >> 16) * 64 + lane];
            float g3 = (float)G0[(size_t)(k3 >> 16) * 64 + lane];
            float g4v = (float)G0[(size_t)(k4 >> 16) * 64 + lane];
            float g5 = (float)G0[(size_t)(k5 >> 16) * 64 + lane];
            float g6 = (float)G0[(size_t)(k6 >> 16) * 64 + lane];
            float g7 = (float)G0[(size_t)(k7 >> 16) * 64 + lane];
            acc += silu_f(hv0 + g0) + silu_f(hv1 + g1)
                 + silu_f(hv2 + g2) + silu_f(hv3 + g3)
                 + silu_f(hv4 + g4v) + silu_f(hv5 + g5)
                 + silu_f(hv6 + g6) + silu_f(hv7 + g7);
        }
        for (; p + 4 <= ke; p += 4) {
            unsigned int k0 = epack[p],     k1 = epack[p + 1],
                         k2 = epack[p + 2], k3 = epack[p + 3];
            float hv0 = (float)hp16[(size_t)(k0 & 0xFFFFu) * 64 + lane];
            float hv1 = (float)hp16[(size_t)(k1 & 0xFFFFu) * 64 + lane];
            float hv2 = (float)hp16[(size_t)(k2 & 0xFFFFu) * 64 + lane];
            float hv3 = (float)hp16[(size_t)(k3 & 0xFFFFu) * 64 + lane];
            float g0 = (float)G0[(size_t)(k0 >> 16) * 64 + lane];
            float g1 = (float)G0[(size_t)(k1 >> 16) * 64 + lane];
            float g2 = (float)G0[(size_t)(k2 >> 16) * 64 + lane];
            float g3 = (float)G0[(size_t)(k3 >> 16) * 64 + lane];
            acc += silu_f(hv0 + g0) + silu_f(hv1 + g1)
                 + silu_f(hv2 + g2) + silu_f(hv3 + g3);
        }
        for (; p < ke; ++p) {
            unsigned int k0 = epack[p];
            acc += silu_f((float)hp16[(size_t)(k0 & 0xFFFFu) * 64 + lane]
                        + (float)G0[(size_t)(k0 >> 16) * 64 + lane]);
        }
        float m = acc * __builtin_amdgcn_rcpf((float)(ke - kb0));
        Sm[(size_t)n * 64 + lane] = (f16)m;
    }
}

// ---------- node kernel: aggr MLP + f16 residual + LN + fused next H' ----------
#define NK_TILES 3125
#define NK_BLOCKS 391

__global__ __launch_bounds__(512, 6)
void k_node(const f16* __restrict__ h16, const f16* __restrict__ Sm,
            const int* __restrict__ rowptr,
            const f16* __restrict__ w2t, const float* __restrict__ b2,
            const f16* __restrict__ u1t, const float* __restrict__ b1u,
            const f16* __restrict__ u2t, const float* __restrict__ b2u,
            const float* __restrict__ lng, const float* __restrict__ lnb,
            const f16* __restrict__ w1an,
            f16* __restrict__ h16o, f16* __restrict__ hp16o,
            float* __restrict__ out32) {
    __shared__ f16 u1s[64 * 128];
    __shared__ f16 w2s[64 * 64], u2s[64 * 64];
    __shared__ float b2s[64], b1us[64], b2us[64], lngs[64], lnbs[64];
    __shared__ f16 trs[8][16 * 64];

    int tid = threadIdx.x;
    {
        const f16x8* u1v = (const f16x8*)u1t;
        #pragma unroll
        for (int it = 0; it < 2; ++it) {
            int g = tid + it * 512;
            int c = g >> 4, k0 = (g & 15) << 3;
            *(f16x8*)&u1s[(c << 7) | (k0 ^ ((c & 7) << 3))] = u1v[g];
        }
        const f16x8* w2v = (const f16x8*)w2t;
        const f16x8* u2v = (const f16x8*)u2t;
        {
            int g = tid;
            int c = g >> 3, k0 = (g & 7) << 3;
            int pp = (c << 6) | (k0 ^ ((c & 7) << 3));
            *(f16x8*)&w2s[pp] = w2v[g];
            *(f16x8*)&u2s[pp] = u2v[g];
        }
    }
    if (tid < 64) {
        b2s[tid] = b2[tid]; b1us[tid] = b1u[tid]; b2us[tid] = b2u[tid];
        lngs[tid] = lng[tid]; lnbs[tid] = lnb[tid];
    }
    __syncthreads();

    int w = tid >> 6, lane = tid & 63;
    int row = lane & 15, g4 = lane >> 4;
    f16* tp = trs[w];

    int tile = blockIdx.x * 8 + w;
    if (tile >= NK_TILES) return;
    int n0 = tile * 16;
    int nA = n0 + row;

    // ---- aggr = mean @ W2 + b2*(deg>0); Sm holds the f16 mean ----
    int degA = rowptr[nA + 1] - rowptr[nA];
    f16x8 sa0 = *(const f16x8*)&Sm[(size_t)nA * 64 + g4 * 8];
    f16x8 sa1 = *(const f16x8*)&Sm[(size_t)nA * 64 + 32 + g4 * 8];
    if (degA <= 0) {
        #pragma unroll
        for (int j = 0; j < 8; ++j) { sa0[j] = (f16)0.f; sa1[j] = (f16)0.f; }
    }
    int nC = n0 + g4 * 4;
    int r0 = rowptr[nC], r1 = rowptr[nC + 1], r2 = rowptr[nC + 2],
        r3 = rowptr[nC + 3], r4 = rowptr[nC + 4];
    float f0 = r1 > r0 ? 1.f : 0.f;
    float f1 = r2 > r1 ? 1.f : 0.f;
    float f2 = r3 > r2 ? 1.f : 0.f;
    float f3 = r4 > r3 ? 1.f : 0.f;

    f32x4 agg[4];
    #pragma unroll
    for (int cb = 0; cb < 4; ++cb) {
        int c = row + 16 * cb;
        float bv = b2s[c];
        agg[cb] = (f32x4){bv * f0, bv * f1, bv * f2, bv * f3};
        f16x8 wb0 = *(const f16x8*)&w2s[(c << 6) | ((g4 * 8) ^ ((c & 7) << 3))];
        f16x8 wb1 = *(const f16x8*)&w2s[(c << 6) | ((32 + g4 * 8) ^ ((c & 7) << 3))];
        agg[cb] = MFMA16(sa0, wb0, agg[cb]);
        agg[cb] = MFMA16(sa1, wb1, agg[cb]);
    }

    // ---- transpose aggr (C-frag) -> A-frag via wave-private LDS ----
    #pragma unroll
    for (int cb = 0; cb < 4; ++cb) {
        int c = row + 16 * cb;
        #pragma unroll
        for (int v = 0; v < 4; ++v) {
            int r = g4 * 4 + v;
            tp[(r << 6) | (c ^ ((r & 7) << 3))] = (f16)agg[cb][v];
        }
    }
    f16x8 ha0 = *(const f16x8*)&h16[(size_t)nA * 64 + g4 * 8];
    f16x8 ha1 = *(const f16x8*)&h16[(size_t)nA * 64 + 32 + g4 * 8];
    f16x8 aa2 = *(const f16x8*)&tp[(row << 6) | ((g4 * 8) ^ ((row & 7) << 3))];
    f16x8 aa3 = *(const f16x8*)&tp[(row << 6) | ((32 + g4 * 8) ^ ((row & 7) << 3))];

    // ---- hid = silu(cat[h, aggr] @ U1 + b1u) ----
    f32x4 hid[4];
    #pragma unroll
    for (int cb = 0; cb < 4; ++cb) {
        int c = row + 16 * cb;
        float bv = b1us[c];
        hid[cb] = (f32x4){bv, bv, bv, bv};
        hid[cb] = MFMA16(ha0, *(const f16x8*)&u1s[(c << 7) | ((g4 * 8) ^ ((c & 7) << 3))], hid[cb]);
        hid[cb] = MFMA16(ha1, *(const f16x8*)&u1s[(c << 7) | ((32 + g4 * 8) ^ ((c & 7) << 3))], hid[cb]);
        hid[cb] = MFMA16(aa2, *(const f16x8*)&u1s[(c << 7) | ((64 + g4 * 8) ^ ((c & 7) << 3))], hid[cb]);
        hid[cb] = MFMA16(aa3, *(const f16x8*)&u1s[(c << 7) | ((96 + g4 * 8) ^ ((c & 7) << 3))], hid[cb]);
    }

    #pragma unroll
    for (int cb = 0; cb < 4; ++cb) {
        int c = row + 16 * cb;
        #pragma unroll
        for (int v = 0; v < 4; ++v) {
            int r = g4 * 4 + v;
            tp[(r << 6) | (c ^ ((r & 7) << 3))] = (f16)silu_f(hid[cb][v]);
        }
    }
    f16x8 za0 = *(const f16x8*)&tp[(row << 6) | ((g4 * 8) ^ ((row & 7) << 3))];
    f16x8 za1 = *(const f16x8*)&tp[(row << 6) | ((32 + g4 * 8) ^ ((row & 7) << 3))];

    f32x4 out[4];
    #pragma unroll
    for (int cb = 0; cb < 4; ++cb) {
        int c = row + 16 * cb;
        float bv = b2us[c];
        out[cb] = (f32x4){bv, bv, bv, bv};
        out[cb] = MFMA16(za0, *(const f16x8*)&u2s[(c << 6) | ((g4 * 8) ^ ((c & 7) << 3))], out[cb]);
        out[cb] = MFMA16(za1, *(const f16x8*)&u2s[(c << 6) | ((32 + g4 * 8) ^ ((c & 7) << 3))], out[cb]);
    }

    // ---- residual (f16 h) + LayerNorm; stash h_new into tp for fused next H' ----
    #pragma unroll
    for (int v = 0; v < 4; ++v) {
        int n = nC + v;
        float hp[4];
        float s = 0.f, q = 0.f;
        #pragma unroll
        for (int cb = 0; cb < 4; ++cb) {
            float xv = (float)h16[(size_t)n * 64 + row + 16 * cb] + out[cb][v];
            hp[cb] = xv; s += xv; q += xv * xv;
        }
        #pragma unroll
        for (int off = 1; off < 16; off <<= 1) {
            s += __shfl_xor(s, off, 64);
            q += __shfl_xor(q, off, 64);
        }
        float mu = s * 0.015625f;
        float var = q * 0.015625f - mu * mu;
        float rstd = __builtin_amdgcn_rsqf(var + EPSF);
        int r = g4 * 4 + v;
        #pragma unroll
        for (int cb = 0; cb < 4; ++cb) {
            int c = row + 16 * cb;
            float o = (hp[cb] - mu) * rstd * lngs[c] + lnbs[c];
            if (out32) out32[(size_t)n * 64 + c] = o;
            f16 o16 = (f16)o;
            if (h16o) h16o[(size_t)n * 64 + c] = o16;
            tp[(r << 6) | (c ^ ((r & 7) << 3))] = o16;
        }
    }

    // ---- fused next-layer H' = h_new @ W1a (B-frags from global/L2) ----
    if (w1an) {
        f16x8 pa0 = *(const f16x8*)&tp[(row << 6) | ((g4 * 8) ^ ((row & 7) << 3))];
        f16x8 pa1 = *(const f16x8*)&tp[(row << 6) | ((32 + g4 * 8) ^ ((row & 7) << 3))];
        #pragma unroll
        for (int cb = 0; cb < 4; ++cb) {
            int c = row + 16 * cb;
            f32x4 acc = (f32x4){0.f, 0.f, 0.f, 0.f};
            f16x8 wb0 = *(const f16x8*)&w1an[c * 128 + g4 * 8];
            f16x8 wb1 = *(const f16x8*)&w1an[c * 128 + 32 + g4 * 8];
            acc = MFMA16(pa0, wb0, acc);
            acc = MFMA16(pa1, wb1, acc);
            #pragma unroll
            for (int v = 0; v < 4; ++v)
                hp16o[(size_t)(nC + v) * 64 + c] = (f16)acc[v];
        }
    }
}

extern "C" void kernel_launch(void* const* d_in, const int* in_sizes, int n_in,
                              void* d_out, int out_size, void* d_ws, size_t ws_size,
                              hipStream_t stream) {
    const float* x   = (const float*)d_in[0];
    const int*   ei  = (const int*)d_in[1];
    const float* ea  = (const float*)d_in[2];
    const float* nW  = (const float*)d_in[3];
    const float* nb  = (const float*)d_in[4];
    const float* eW  = (const float*)d_in[5];
    const float* eb  = (const float*)d_in[6];
    const float* mW1 = (const float*)d_in[7];
    const float* mb1 = (const float*)d_in[8];
    const float* mW2 = (const float*)d_in[9];
    const float* mb2 = (const float*)d_in[10];
    const float* uW1 = (const float*)d_in[11];
    const float* ub1 = (const float*)d_in[12];
    const float* uW2 = (const float*)d_in[13];
    const float* ub2 = (const float*)d_in[14];
    const float* lng = (const float*)d_in[15];
    const float* lnb = (const float*)d_in[16];

    char* p = (char*)d_ws;
    f16*   Sm     = (f16*)p;    p += (size_t)NN * 64 * 2;
    f16*   h16    = (f16*)p;    p += (size_t)NN * 64 * 2;
    f16*   hp16   = (f16*)p;    p += (size_t)NN * 64 * 2;
    int*   rowptr = (int*)p;    p += (size_t)(NN + 4) * 4;
    int*   ghist  = (int*)p;    p += (size_t)NBKT * BK_BLOCKS * 4;
    int*   tot    = (int*)p;    p += (size_t)(NBKT + 4) * 4;
    int*   bstart = (int*)p;    p += (size_t)(NBKT + 4) * 4;
    int*   wstart = (int*)p;    p += (size_t)(NWAVE + 4) * 4;
    unsigned int* epack = (unsigned int*)p; p += (size_t)NE * 4;
    unsigned long long* btmp = (unsigned long long*)p; p += (size_t)NE * 8;
    f16*   G      = (f16*)p;    p += (size_t)DEPTH * GROWS * 64 * 2;
    f16*   w1t = (f16*)p;    p += (size_t)DEPTH * 8192 * 2;
    f16*   w2t = (f16*)p;    p += (size_t)DEPTH * 4096 * 2;
    f16*   u1t = (f16*)p;    p += (size_t)DEPTH * 8192 * 2;
    f16*   u2t = (f16*)p;    p += (size_t)DEPTH * 4096 * 2;

    k_prep<<<NB_PREP, 256, 0, stream>>>(mW1, mW2, uW1, uW2, w1t, w2t, u1t, u2t,
                                        x, nW, nb, h16, eW, eb, mb1, G, ei, ghist);
    k_bscan1<<<(NBKT + 3) / 4, 256, 0, stream>>>(ghist, tot);
    k_bscan2<<<1, 64, 0, stream>>>(tot, bstart);
    k_bscatter<<<BK_BLOCKS, 256, 0, stream>>>(ei, ea, ghist, bstart, btmp);
    k_csr<<<NBKT, 1024, 0, stream>>>(btmp, bstart, rowptr, epack);
    k_wstart<<<(NWAVE + 256) / 256, 256, 0, stream>>>(rowptr, wstart);
    k_hprime<<<HP_BLOCKS, 512, 0, stream>>>(h16, w1t, hp16);   // layer 0 H'

    for (int l = 0; l < DEPTH; ++l) {
        bool last = (l == DEPTH - 1);
        k_edge<<<EK_BLOCKS, 256, 0, stream>>>(rowptr, wstart, epack, hp16,
            G + (size_t)l * GROWS * 64, Sm);
        k_node<<<NK_BLOCKS, 512, 0, stream>>>(h16, Sm, rowptr,
            w2t + (size_t)l * 4096, mb2 + l * 64,
            u1t + (size_t)l * 8192, ub1 + l * 64,
            u2t + (size_t)l * 4096, ub2 + l * 64,
            lng + l * 64, lnb + l * 64,
            last ? (const f16*)nullptr : (w1t + (size_t)(l + 1) * 8192),
            last ? (f16*)nullptr : h16, hp16,
            last ? (float*)d_out : (float*)nullptr);
    }
}